// Round 13
// baseline (287.994 us; speedup 1.0000x reference)
//
#include <hip/hip_runtime.h>
#include <math.h>

#define N_NODES 100000
#define N_EDGES 1600000
#define N_GRAPHS 512
#define BN_EPS 1e-5f

#define NBUCKET 1024                            // dst>>7 -> 782 used
#define NBUCKET_USED ((N_NODES + 127) / 128)    // 782
#define SLOT 2560                               // slab capacity per bucket (mean 2048, sd 45)
#define BCHUNK 8192                             // edges per bin_scatter block
#define NCHUNKS ((N_EDGES + BCHUNK - 1) / BCHUNK)  // 196

typedef unsigned int uint;
typedef unsigned short ushort;
typedef unsigned char uchar;
typedef _Float16 f16;
typedef _Float16 f16x8 __attribute__((ext_vector_type(8)));
typedef float f32x4 __attribute__((ext_vector_type(4)));
typedef float f32x2 __attribute__((ext_vector_type(2)));

// ---------------- workspace layout (bytes) ----------------
constexpr size_t OFF_BCUR = 0;          // int[1024] bucket cursors (zeroed by init_prep)
constexpr size_t OFF_DIS  = 4096;       // float[N] rsqrt(deg+1)
constexpr size_t OFF_ROW  = 404096;     // int[N] CSR row starts (slab-absolute)
constexpr size_t OFF_END  = 804096;     // int[N] CSR row ends
constexpr size_t OFF_WT   = 1204096;    // f16[128*128 + 64*128] W1^T,W2^T
constexpr size_t OFF_BIN  = 1253248;    // uint[1024*2560] binned slabs = 10.5MB
constexpr size_t OFF_CSR  = 11739008;   // int[1024*2560] CSR slabs = 10.5MB
constexpr size_t OFF_P    = 22224768;   // M2 fp8 [N*64] = 6.4MB
constexpr size_t OFF_Q    = 28624768;   // M1 fp8 [N*128] = 12.8MB

__device__ __forceinline__ uint packf16(float a, float b) {
    union { f16 h[2]; uint u; } z;
    z.h[0] = (f16)a; z.h[1] = (f16)b;
    return z.u;
}
__device__ __forceinline__ uchar f2fp8(float v) {
    return (uchar)(__builtin_amdgcn_cvt_pk_fp8_f32(v, v, 0, false) & 0xff);
}

// ---------------- init: W^T in f16 (blocks 0..95) + zero cursors (block 96) ----------------
__global__ __launch_bounds__(256) void init_prep(const float* __restrict__ W1,
                                                 const float* __restrict__ W2,
                                                 f16* __restrict__ wT,
                                                 int* __restrict__ bcur) {
    int b = blockIdx.x;
    if (b == 96) {
        int t = threadIdx.x;
        bcur[t] = 0; bcur[t + 256] = 0; bcur[t + 512] = 0; bcur[t + 768] = 0;
        return;
    }
    int tid = b * 256 + threadIdx.x;
    if (tid < 16384) {                    // W1^T: wT[n*128+k] = W1[k*128+n]
        int n = tid >> 7, k = tid & 127;
        wT[tid] = (f16)W1[k * 128 + n];
    } else {                              // W2^T
        int t = tid - 16384;
        int n = t >> 7, k = t & 127;
        wT[tid] = (f16)W2[k * 64 + n];
    }
}

// ---- pass 1: bin edges by dst>>7 into fixed slabs. Per-edge atomics in LDS only;
// ---- one global atomicAdd per (block,bucket) reserves a run in the bucket's slab. ----
__global__ __launch_bounds__(1024) void bin_scatter(const int* __restrict__ src,
                                                    const int* __restrict__ dst,
                                                    int* __restrict__ bcur,
                                                    uint* __restrict__ binned) {
    constexpr int REG = BCHUNK / 1024;           // 8 edges per thread
    __shared__ int hist[NBUCKET];                // pass A: counts; pass B: local cursors
    __shared__ int base[NBUCKET];                // slab-local run base for this block
    int t = threadIdx.x;
    int e0 = blockIdx.x * BCHUNK;
    int lim = N_EDGES - e0;

    hist[t] = 0;
    __syncthreads();

    int ds[REG], ss[REG];
#pragma unroll
    for (int i = 0; i < REG; ++i) {
        int idx = t + i * 1024;
        if (idx < lim) {
            ds[i] = dst[e0 + idx];
            ss[i] = src[e0 + idx];
            atomicAdd(&hist[ds[i] >> 7], 1);
        }
    }
    __syncthreads();

    int h = hist[t];
    base[t] = h ? atomicAdd(&bcur[t], h) : 0;    // block-level reservation in slab
    hist[t] = 0;                                 // reuse as local cursor
    __syncthreads();

#pragma unroll
    for (int i = 0; i < REG; ++i) {
        int idx = t + i * 1024;
        if (idx < lim) {
            int b = ds[i] >> 7;
            int pos = b * SLOT + base[b] + atomicAdd(&hist[b], 1);
            binned[pos] = ((uint)ss[i] << 7) | (uint)(ds[i] & 127);
        }
    }
}

// ---- pass 2: one block per bucket. LDS count + scan -> row_start/row_end, dis,
// ---- placed csr_src (slab-organized). Zero global atomics. ----
__global__ __launch_bounds__(256) void csr_from_bins(const uint* __restrict__ binned,
                                                     const int* __restrict__ bcur,
                                                     int* __restrict__ row_start,
                                                     int* __restrict__ row_end,
                                                     float* __restrict__ dis,
                                                     int* __restrict__ csr_src) {
    __shared__ int cnt[128];
    __shared__ int ex[128];
    int t = threadIdx.x;
    int b = blockIdx.x;
    if (t < 128) cnt[t] = 0;
    __syncthreads();
    int base = b * SLOT;
    int nb = bcur[b];                            // edges in this bucket
    for (int i = t; i < nb; i += 256)
        atomicAdd(&cnt[binned[base + i] & 127u], 1);
    __syncthreads();
    if (t < 128) ex[t] = cnt[t];
    __syncthreads();
    for (int off = 1; off < 128; off <<= 1) {
        int v = (t < 128 && t >= off) ? ex[t - off] : 0;
        __syncthreads();
        if (t < 128) ex[t] += v;
        __syncthreads();
    }
    if (t < 128) {
        int c = cnt[t];
        ex[t] -= c;                              // exclusive
        int node = b * 128 + t;
        if (node < N_NODES) {
            int rs = base + ex[t];
            row_start[node] = rs;
            row_end[node] = rs + c;
            dis[node] = rsqrtf((float)(c + 1));  // +1 self-loop
        }
        cnt[t] = 0;                              // reuse as cursor
    }
    __syncthreads();
    for (int i = t; i < nb; i += 256) {
        uint p = binned[base + i];
        int s = (int)(p >> 7);
        int d = (int)(p & 127u);
        int pos = base + ex[d] + atomicAdd(&cnt[d], 1);
        csr_src[pos] = s;
    }
}

// ---------------- MFMA GEMM layer 1: A = f32 x, scaled by dis; output M1 = fp8 ----------------
__global__ __launch_bounds__(256) void gemm_mfma1(const float* __restrict__ X,
                                                  const float* __restrict__ dis,
                                                  const f16* __restrict__ Bt,
                                                  uchar* __restrict__ Y) {
    constexpr int NT = 8;                 // OUTF = 128
    constexpr int PITCH = 136;
    __shared__ f16 sA[64 * PITCH];
    __shared__ f16 sB[128 * PITCH];
    int tid = threadIdx.x;
    int n0 = blockIdx.x * 64;

    for (int i = tid; i < 64 * 16; i += 256) {
        int r = i >> 4, c = i & 15;
        int n = n0 + r;
        uint4 pk = make_uint4(0, 0, 0, 0);
        if (n < N_NODES) {
            const float4* px = (const float4*)(X + (size_t)n * 128);
            float4 u = px[c * 2], v = px[c * 2 + 1];
            float d = dis[n];
            pk.x = packf16(u.x * d, u.y * d);
            pk.y = packf16(u.z * d, u.w * d);
            pk.z = packf16(v.x * d, v.y * d);
            pk.w = packf16(v.z * d, v.w * d);
        }
        *(uint4*)&sA[r * PITCH + c * 8] = pk;
    }
    for (int i = tid; i < 128 * 16; i += 256) {
        int r = i >> 4, c = i & 15;
        *(uint4*)&sB[r * PITCH + c * 8] = ((const uint4*)(Bt + r * 128))[c];
    }
    __syncthreads();

    int lane = tid & 63, wave = tid >> 6;
    int l15 = lane & 15, q = lane >> 4;
    int m0 = wave * 16;
    f32x4 acc[NT];
#pragma unroll
    for (int nt = 0; nt < NT; ++nt) acc[nt] = (f32x4){0.f, 0.f, 0.f, 0.f};

    const f16* pa = &sA[(m0 + l15) * PITCH + q * 8];
    const f16* pb = &sB[l15 * PITCH + q * 8];
#pragma unroll
    for (int kk = 0; kk < 4; ++kk) {
        f16x8 a = *(const f16x8*)(pa + kk * 32);
#pragma unroll
        for (int nt = 0; nt < NT; ++nt) {
            f16x8 b = *(const f16x8*)(pb + nt * 16 * PITCH + kk * 32);
            acc[nt] = __builtin_amdgcn_mfma_f32_16x16x32_f16(a, b, acc[nt], 0, 0, 0);
        }
    }

    int row_base = n0 + m0 + q * 4;                     // C/D: col=lane&15, row=q*4+reg
#pragma unroll
    for (int nt = 0; nt < NT; ++nt) {
#pragma unroll
        for (int r = 0; r < 4; ++r) {
            int row = row_base + r;
            if (row < N_NODES)
                Y[(size_t)row * 128 + nt * 16 + l15] = f2fp8(acc[nt][r]);
        }
    }
}

// ---- aggregation L1 FUSED with GEMM2. M1 fp8 rows (128B). Each wave aggregates
// ---- 4 nodes (full-wave gathers, 16 in flight), h1s -> LDS f16, then
// ---- 16x64 MFMA vs W2^T -> M2 fp8.
__global__ __launch_bounds__(256) void aggregate1_fused(const ushort* __restrict__ M,
                                                        const int* __restrict__ row_start,
                                                        const int* __restrict__ row_end,
                                                        const int* __restrict__ csr_src,
                                                        const float* __restrict__ dis,
                                                        const float* __restrict__ bias,
                                                        const f16* __restrict__ W2t,
                                                        uchar* __restrict__ M2) {
    constexpr int PITCH = 136;            // sB pitch in f16
    constexpr int HP = 130;               // sH pitch in f16 (65 uints)
    __shared__ f16 sB[64 * PITCH];
    __shared__ f16 sH[16 * HP];
    int tid = threadIdx.x;
    // stage W2^T [64 out][128 k]
    for (int i = tid; i < 64 * 16; i += 256) {
        int r = i >> 4, c = i & 15;
        *(uint4*)&sB[r * PITCH + c * 8] = ((const uint4*)(W2t + r * 128))[c];
    }
    int wv = __builtin_amdgcn_readfirstlane((int)(tid >> 6));
    int lane = tid & 63;
    int n0 = blockIdx.x * 16;             // 100000 = 6250 * 16 exactly

    for (int i = 0; i < 4; ++i) {
        int r = wv * 4 + i;
        int n = n0 + r;
        float dn = dis[n];
        int e0 = row_start[n], e1 = row_end[n];
        f32x2 t0 = __builtin_amdgcn_cvt_pk_f32_fp8((int)M[(size_t)n * 64 + lane], false);
        float a0 = t0.x, a1 = t0.y, b0 = 0.f, b1v = 0.f;
        int e = e0;
        for (; e + 16 <= e1; e += 16) {
            int s[16];
#pragma unroll
            for (int j = 0; j < 16; ++j) s[j] = csr_src[e + j];
            ushort v[16];
#pragma unroll
            for (int j = 0; j < 16; ++j) v[j] = M[(size_t)s[j] * 64 + lane];
#pragma unroll
            for (int j = 0; j < 16; ++j) {
                f32x2 f = __builtin_amdgcn_cvt_pk_f32_fp8((int)v[j], false);
                if (j & 1) { b0 += f.x; b1v += f.y; } else { a0 += f.x; a1 += f.y; }
            }
        }
        for (; e + 8 <= e1; e += 8) {
            int s[8];
#pragma unroll
            for (int j = 0; j < 8; ++j) s[j] = csr_src[e + j];
            ushort v[8];
#pragma unroll
            for (int j = 0; j < 8; ++j) v[j] = M[(size_t)s[j] * 64 + lane];
#pragma unroll
            for (int j = 0; j < 8; ++j) {
                f32x2 f = __builtin_amdgcn_cvt_pk_f32_fp8((int)v[j], false);
                if (j & 1) { b0 += f.x; b1v += f.y; } else { a0 += f.x; a1 += f.y; }
            }
        }
        for (; e + 4 <= e1; e += 4) {
            int s0 = csr_src[e], s1 = csr_src[e + 1], s2 = csr_src[e + 2], s3 = csr_src[e + 3];
            ushort v0 = M[(size_t)s0 * 64 + lane];
            ushort v1 = M[(size_t)s1 * 64 + lane];
            ushort v2 = M[(size_t)s2 * 64 + lane];
            ushort v3 = M[(size_t)s3 * 64 + lane];
            f32x2 f0 = __builtin_amdgcn_cvt_pk_f32_fp8((int)v0, false);
            f32x2 f1 = __builtin_amdgcn_cvt_pk_f32_fp8((int)v1, false);
            f32x2 f2 = __builtin_amdgcn_cvt_pk_f32_fp8((int)v2, false);
            f32x2 f3 = __builtin_amdgcn_cvt_pk_f32_fp8((int)v3, false);
            a0 += f0.x + f1.x; a1 += f0.y + f1.y;
            b0 += f2.x + f3.x; b1v += f2.y + f3.y;
        }
        for (; e < e1; ++e) {
            f32x2 f = __builtin_amdgcn_cvt_pk_f32_fp8((int)M[(size_t)csr_src[e] * 64 + lane], false);
            a0 += f.x; a1 += f.y;
        }
        a0 += b0; a1 += b1v;
        a0 = fmaxf(fmaf(a0, dn, bias[2 * lane]), 0.f) * dn;
        a1 = fmaxf(fmaf(a1, dn, bias[2 * lane + 1]), 0.f) * dn;
        *(uint*)&sH[r * HP + 2 * lane] = packf16(a0, a1);   // h1s row r in LDS (f16)
    }
    __syncthreads();

    // MFMA: C[16 nodes][64 out] ; wave wv covers out cols wv*16..wv*16+15
    int l15 = lane & 15, q = lane >> 4;
    f32x4 acc = (f32x4){0.f, 0.f, 0.f, 0.f};
    const f16* pa = &sH[l15 * HP + q * 8];
    const f16* pb = &sB[(wv * 16 + l15) * PITCH + q * 8];
#pragma unroll
    for (int kk = 0; kk < 4; ++kk) {
        f16x8 a = *(const f16x8*)(pa + kk * 32);
        f16x8 b = *(const f16x8*)(pb + kk * 32);
        acc = __builtin_amdgcn_mfma_f32_16x16x32_f16(a, b, acc, 0, 0, 0);
    }
    int row_base = n0 + q * 4;                    // C/D: col=lane&15, row=q*4+reg
#pragma unroll
    for (int rr = 0; rr < 4; ++rr)
        M2[(size_t)(row_base + rr) * 64 + wv * 16 + l15] = f2fp8(acc[rr]);
}

// ---- aggregation L2 FUSED with pooling: one block per graph (batch sorted).
// ---- 8 waves; wave w handles nodes start+w, start+w+8, ... Each node: full-wave
// ---- 64B fp8 row gathers (16 in flight), h2 row stays in registers, accumulated
// ---- into per-wave pooled partial. LDS combine -> pooled[g]. No h2 buffer. ----
__global__ __launch_bounds__(512) void agg2_pool(const uchar* __restrict__ M,
                                                 const int* __restrict__ row_start,
                                                 const int* __restrict__ row_end,
                                                 const int* __restrict__ csr_src,
                                                 const float* __restrict__ dis,
                                                 const float* __restrict__ bias,
                                                 const int* __restrict__ batch,
                                                 float* __restrict__ pooled) {
    __shared__ float part[8][64];
    int g = blockIdx.x;
    int tid = threadIdx.x;
    int wv = tid >> 6, lane = tid & 63;
    int lo = 0, hi = N_NODES;
    while (lo < hi) { int mid = (lo + hi) >> 1; if (batch[mid] < g) lo = mid + 1; else hi = mid; }
    int start = lo;
    hi = N_NODES;
    while (lo < hi) { int mid = (lo + hi) >> 1; if (batch[mid] < g + 1) lo = mid + 1; else hi = mid; }
    int end = lo;
    float bl = bias[lane];
    float pacc = 0.f;
    for (int nn = start + wv; nn < end; nn += 8) {
        int n = __builtin_amdgcn_readfirstlane(nn);
        float dn = dis[n];
        int e0 = row_start[n], e1 = row_end[n];
        float a0 = __builtin_amdgcn_cvt_f32_fp8((int)M[(size_t)n * 64 + lane], 0);  // self-loop
        float a1 = 0.f;
        int e = e0;
        for (; e + 16 <= e1; e += 16) {
            int s[16];
#pragma unroll
            for (int j = 0; j < 16; ++j) s[j] = csr_src[e + j];
            uchar v[16];
#pragma unroll
            for (int j = 0; j < 16; ++j) v[j] = M[(size_t)s[j] * 64 + lane];
#pragma unroll
            for (int j = 0; j < 16; ++j) {
                float f = __builtin_amdgcn_cvt_f32_fp8((int)v[j], 0);
                if (j & 1) a1 += f; else a0 += f;
            }
        }
        for (; e + 8 <= e1; e += 8) {
            int s[8];
#pragma unroll
            for (int j = 0; j < 8; ++j) s[j] = csr_src[e + j];
            uchar v[8];
#pragma unroll
            for (int j = 0; j < 8; ++j) v[j] = M[(size_t)s[j] * 64 + lane];
#pragma unroll
            for (int j = 0; j < 8; ++j) {
                float f = __builtin_amdgcn_cvt_f32_fp8((int)v[j], 0);
                if (j & 1) a1 += f; else a0 += f;
            }
        }
        for (; e + 4 <= e1; e += 4) {
            int s0 = csr_src[e], s1 = csr_src[e + 1], s2 = csr_src[e + 2], s3 = csr_src[e + 3];
            float v0 = __builtin_amdgcn_cvt_f32_fp8((int)M[(size_t)s0 * 64 + lane], 0);
            float v1 = __builtin_amdgcn_cvt_f32_fp8((int)M[(size_t)s1 * 64 + lane], 0);
            float v2 = __builtin_amdgcn_cvt_f32_fp8((int)M[(size_t)s2 * 64 + lane], 0);
            float v3 = __builtin_amdgcn_cvt_f32_fp8((int)M[(size_t)s3 * 64 + lane], 0);
            a0 += v0 + v1; a1 += v2 + v3;
        }
        for (; e < e1; ++e)
            a0 += __builtin_amdgcn_cvt_f32_fp8((int)M[(size_t)csr_src[e] * 64 + lane], 0);
        a0 += a1;
        pacc += fmaxf(fmaf(a0, dn, bl), 0.f);
    }
    part[wv][lane] = pacc;
    __syncthreads();
    if (wv == 0) {
        float s = part[0][lane] + part[1][lane] + part[2][lane] + part[3][lane]
                + part[4][lane] + part[5][lane] + part[6][lane] + part[7][lane];
        pooled[g * 64 + lane] = s;
    }
}

// ---------------- BN stats + head fused (single block, 512 threads) ----------------
__global__ __launch_bounds__(512) void bn_head(const float* __restrict__ pooled,
                                               const float* __restrict__ gamma,
                                               const float* __restrict__ beta,
                                               const float* __restrict__ Wo1,
                                               const float* __restrict__ bo1,
                                               const float* __restrict__ Wo2,
                                               const float* __restrict__ bo2,
                                               float* __restrict__ out) {
    __shared__ float sW1[64 * 24];
    __shared__ float sW2[24];
    __shared__ float sb1[24];
    __shared__ float ssc[64];
    __shared__ float ssh[64];
    int tid = threadIdx.x;
    for (int i = tid; i < 64 * 24; i += 512) sW1[i] = Wo1[i];
    if (tid >= 64 && tid < 88) { int k = tid - 64; sW2[k] = Wo2[k]; sb1[k] = bo1[k]; }
    if (tid < 64) {
        float s = 0.f, s2 = 0.f;
        for (int g = 0; g < N_GRAPHS; ++g) {
            float v = pooled[g * 64 + tid];
            s += v;
            s2 = fmaf(v, v, s2);
        }
        float mean = s * (1.0f / N_GRAPHS);
        float var = s2 * (1.0f / N_GRAPHS) - mean * mean;
        float istd = rsqrtf(var + BN_EPS);
        float sc = gamma[tid] * istd;
        ssc[tid] = sc;
        ssh[tid] = beta[tid] - mean * sc;
    }
    __syncthreads();
    int g = tid;                                  // 512 graphs = 512 threads
    float xn[64];
    const float* pr = pooled + g * 64;
#pragma unroll
    for (int j = 0; j < 64; ++j) xn[j] = fmaf(pr[j], ssc[j], ssh[j]);
    float o = bo2[0];
#pragma unroll 4
    for (int k = 0; k < 24; ++k) {
        float h = sb1[k];
#pragma unroll
        for (int j = 0; j < 64; ++j) h = fmaf(xn[j], sW1[j * 24 + k], h);
        o = fmaf(fmaxf(h, 0.f), sW2[k], o);
    }
    out[g] = o;
}

extern "C" void kernel_launch(void* const* d_in, const int* in_sizes, int n_in,
                              void* d_out, int out_size, void* d_ws, size_t ws_size,
                              hipStream_t stream) {
    const float* x     = (const float*)d_in[0];
    const int*   ei    = (const int*)d_in[1];   // [2,E]: first E = src, next E = dst
    const int*   batch = (const int*)d_in[2];
    const float* W1    = (const float*)d_in[3];
    const float* b1    = (const float*)d_in[4];
    const float* W2    = (const float*)d_in[5];
    const float* b2    = (const float*)d_in[6];
    const float* gamma = (const float*)d_in[7];
    const float* beta  = (const float*)d_in[8];
    const float* Wo1   = (const float*)d_in[9];
    const float* bo1   = (const float*)d_in[10];
    const float* Wo2   = (const float*)d_in[11];
    const float* bo2   = (const float*)d_in[12];
    float* out = (float*)d_out;               // [512] out, then [512*64] h(=pooled)
    char* ws = (char*)d_ws;

    const int* srcv = ei;
    const int* dstv = ei + N_EDGES;
    int*    bcur     = (int*)(ws + OFF_BCUR);
    float*  dis      = (float*)(ws + OFF_DIS);
    int*    row_start= (int*)(ws + OFF_ROW);
    int*    row_end  = (int*)(ws + OFF_END);
    f16*    wT       = (f16*)(ws + OFF_WT);
    uint*   binned   = (uint*)(ws + OFF_BIN);
    int*    csr_src  = (int*)(ws + OFF_CSR);
    uchar*  bufP     = (uchar*)(ws + OFF_P);  // M2 (fp8)
    uchar*  bufQ     = (uchar*)(ws + OFF_Q);  // M1 (fp8)
    float*  pooled   = out + N_GRAPHS;        // h output region, also used downstream

    init_prep<<<97, 256, 0, stream>>>(W1, W2, wT, bcur);
    bin_scatter<<<NCHUNKS, 1024, 0, stream>>>(srcv, dstv, bcur, binned);
    csr_from_bins<<<NBUCKET_USED, 256, 0, stream>>>(binned, bcur, row_start, row_end, dis, csr_src);

    int gblocks = (N_NODES + 63) / 64;
    gemm_mfma1<<<gblocks, 256, 0, stream>>>(x, dis, wT, bufQ);
    aggregate1_fused<<<N_NODES / 16, 256, 0, stream>>>((const ushort*)bufQ, row_start, row_end,
                                                       csr_src, dis, b1, wT + 16384, bufP);
    agg2_pool<<<N_GRAPHS, 512, 0, stream>>>(bufP, row_start, row_end, csr_src, dis, b2, batch,
                                            pooled);
    bn_head<<<1, 512, 0, stream>>>(pooled, gamma, beta, Wo1, bo1, Wo2, bo2, out);
}

// Round 14
// 281.481 us; speedup vs baseline: 1.0231x; 1.0231x over previous
//
#include <hip/hip_runtime.h>
#include <math.h>

#define N_NODES 100000
#define N_EDGES 1600000
#define N_GRAPHS 512
#define BN_EPS 1e-5f

#define NBUCKET 1024                            // dst>>7 -> 782 used
#define NBUCKET_USED ((N_NODES + 127) / 128)    // 782
#define SLOT 2560                               // slab capacity per bucket (mean 2048, sd 45)
#define BCHUNK 8192                             // edges per bin_scatter block
#define NCHUNKS ((N_EDGES + BCHUNK - 1) / BCHUNK)  // 196

typedef unsigned int uint;
typedef unsigned short ushort;
typedef unsigned char uchar;
typedef _Float16 f16;
typedef _Float16 f16x8 __attribute__((ext_vector_type(8)));
typedef float f32x4 __attribute__((ext_vector_type(4)));
typedef float f32x2 __attribute__((ext_vector_type(2)));

// ---------------- workspace layout (bytes) ----------------
constexpr size_t OFF_BCUR = 0;          // int[1024] bucket cursors (zeroed by init_prep)
constexpr size_t OFF_DIS  = 4096;       // float[N] rsqrt(deg+1)
constexpr size_t OFF_ROW  = 404096;     // int[N] CSR row starts (slab-absolute)
constexpr size_t OFF_END  = 804096;     // int[N] CSR row ends
constexpr size_t OFF_WT   = 1204096;    // f16[128*128 + 64*128] W1^T,W2^T
constexpr size_t OFF_BIN  = 1253248;    // uint[1024*2560] binned slabs = 10.5MB
constexpr size_t OFF_CSR  = 11739008;   // int[1024*2560] CSR slabs = 10.5MB
constexpr size_t OFF_P    = 22224768;   // M2 fp8 [N*64] = 6.4MB
constexpr size_t OFF_Q    = 28624768;   // M1 fp8 [N*128] = 12.8MB

__device__ __forceinline__ uint packf16(float a, float b) {
    union { f16 h[2]; uint u; } z;
    z.h[0] = (f16)a; z.h[1] = (f16)b;
    return z.u;
}
__device__ __forceinline__ uchar f2fp8(float v) {
    return (uchar)(__builtin_amdgcn_cvt_pk_fp8_f32(v, v, 0, false) & 0xff);
}

// ---- init: W^T f16 (blocks 0..95) + zero cursors (block 96) + zero pooled (97..104) ----
__global__ __launch_bounds__(256) void init_prep(const float* __restrict__ W1,
                                                 const float* __restrict__ W2,
                                                 f16* __restrict__ wT,
                                                 int* __restrict__ bcur,
                                                 float* __restrict__ pooled) {
    int b = blockIdx.x;
    if (b == 96) {
        int t = threadIdx.x;
        bcur[t] = 0; bcur[t + 256] = 0; bcur[t + 512] = 0; bcur[t + 768] = 0;
        return;
    }
    if (b >= 97) {                        // zero pooled: 8 blocks x 256 x 16 floats = 32768
        int base = (b - 97) * 4096 + threadIdx.x * 16;
#pragma unroll
        for (int i = 0; i < 16; ++i) pooled[base + i] = 0.f;
        return;
    }
    int tid = b * 256 + threadIdx.x;
    if (tid < 16384) {                    // W1^T: wT[n*128+k] = W1[k*128+n]
        int n = tid >> 7, k = tid & 127;
        wT[tid] = (f16)W1[k * 128 + n];
    } else {                              // W2^T
        int t = tid - 16384;
        int n = t >> 7, k = t & 127;
        wT[tid] = (f16)W2[k * 64 + n];
    }
}

// ---- pass 1: bin edges by dst>>7 into fixed slabs. Per-edge atomics in LDS only;
// ---- one global atomicAdd per (block,bucket) reserves a run in the bucket's slab. ----
__global__ __launch_bounds__(1024) void bin_scatter(const int* __restrict__ src,
                                                    const int* __restrict__ dst,
                                                    int* __restrict__ bcur,
                                                    uint* __restrict__ binned) {
    constexpr int REG = BCHUNK / 1024;           // 8 edges per thread
    __shared__ int hist[NBUCKET];                // pass A: counts; pass B: local cursors
    __shared__ int base[NBUCKET];                // slab-local run base for this block
    int t = threadIdx.x;
    int e0 = blockIdx.x * BCHUNK;
    int lim = N_EDGES - e0;

    hist[t] = 0;
    __syncthreads();

    int ds[REG], ss[REG];
#pragma unroll
    for (int i = 0; i < REG; ++i) {
        int idx = t + i * 1024;
        if (idx < lim) {
            ds[i] = dst[e0 + idx];
            ss[i] = src[e0 + idx];
            atomicAdd(&hist[ds[i] >> 7], 1);
        }
    }
    __syncthreads();

    int h = hist[t];
    base[t] = h ? atomicAdd(&bcur[t], h) : 0;    // block-level reservation in slab
    hist[t] = 0;                                 // reuse as local cursor
    __syncthreads();

#pragma unroll
    for (int i = 0; i < REG; ++i) {
        int idx = t + i * 1024;
        if (idx < lim) {
            int b = ds[i] >> 7;
            int pos = b * SLOT + base[b] + atomicAdd(&hist[b], 1);
            binned[pos] = ((uint)ss[i] << 7) | (uint)(ds[i] & 127);
        }
    }
}

// ---- pass 2: one block per bucket. LDS count + scan -> row_start/row_end, dis,
// ---- placed csr_src (slab-organized). Zero global atomics. ----
__global__ __launch_bounds__(256) void csr_from_bins(const uint* __restrict__ binned,
                                                     const int* __restrict__ bcur,
                                                     int* __restrict__ row_start,
                                                     int* __restrict__ row_end,
                                                     float* __restrict__ dis,
                                                     int* __restrict__ csr_src) {
    __shared__ int cnt[128];
    __shared__ int ex[128];
    int t = threadIdx.x;
    int b = blockIdx.x;
    if (t < 128) cnt[t] = 0;
    __syncthreads();
    int base = b * SLOT;
    int nb = bcur[b];                            // edges in this bucket
    for (int i = t; i < nb; i += 256)
        atomicAdd(&cnt[binned[base + i] & 127u], 1);
    __syncthreads();
    if (t < 128) ex[t] = cnt[t];
    __syncthreads();
    for (int off = 1; off < 128; off <<= 1) {
        int v = (t < 128 && t >= off) ? ex[t - off] : 0;
        __syncthreads();
        if (t < 128) ex[t] += v;
        __syncthreads();
    }
    if (t < 128) {
        int c = cnt[t];
        ex[t] -= c;                              // exclusive
        int node = b * 128 + t;
        if (node < N_NODES) {
            int rs = base + ex[t];
            row_start[node] = rs;
            row_end[node] = rs + c;
            dis[node] = rsqrtf((float)(c + 1));  // +1 self-loop
        }
        cnt[t] = 0;                              // reuse as cursor
    }
    __syncthreads();
    for (int i = t; i < nb; i += 256) {
        uint p = binned[base + i];
        int s = (int)(p >> 7);
        int d = (int)(p & 127u);
        int pos = base + ex[d] + atomicAdd(&cnt[d], 1);
        csr_src[pos] = s;
    }
}

// ---------------- MFMA GEMM layer 1: A = f32 x, scaled by dis; output M1 = fp8 ----------------
__global__ __launch_bounds__(256) void gemm_mfma1(const float* __restrict__ X,
                                                  const float* __restrict__ dis,
                                                  const f16* __restrict__ Bt,
                                                  uchar* __restrict__ Y) {
    constexpr int NT = 8;                 // OUTF = 128
    constexpr int PITCH = 136;
    __shared__ f16 sA[64 * PITCH];
    __shared__ f16 sB[128 * PITCH];
    int tid = threadIdx.x;
    int n0 = blockIdx.x * 64;

    for (int i = tid; i < 64 * 16; i += 256) {
        int r = i >> 4, c = i & 15;
        int n = n0 + r;
        uint4 pk = make_uint4(0, 0, 0, 0);
        if (n < N_NODES) {
            const float4* px = (const float4*)(X + (size_t)n * 128);
            float4 u = px[c * 2], v = px[c * 2 + 1];
            float d = dis[n];
            pk.x = packf16(u.x * d, u.y * d);
            pk.y = packf16(u.z * d, u.w * d);
            pk.z = packf16(v.x * d, v.y * d);
            pk.w = packf16(v.z * d, v.w * d);
        }
        *(uint4*)&sA[r * PITCH + c * 8] = pk;
    }
    for (int i = tid; i < 128 * 16; i += 256) {
        int r = i >> 4, c = i & 15;
        *(uint4*)&sB[r * PITCH + c * 8] = ((const uint4*)(Bt + r * 128))[c];
    }
    __syncthreads();

    int lane = tid & 63, wave = tid >> 6;
    int l15 = lane & 15, q = lane >> 4;
    int m0 = wave * 16;
    f32x4 acc[NT];
#pragma unroll
    for (int nt = 0; nt < NT; ++nt) acc[nt] = (f32x4){0.f, 0.f, 0.f, 0.f};

    const f16* pa = &sA[(m0 + l15) * PITCH + q * 8];
    const f16* pb = &sB[l15 * PITCH + q * 8];
#pragma unroll
    for (int kk = 0; kk < 4; ++kk) {
        f16x8 a = *(const f16x8*)(pa + kk * 32);
#pragma unroll
        for (int nt = 0; nt < NT; ++nt) {
            f16x8 b = *(const f16x8*)(pb + nt * 16 * PITCH + kk * 32);
            acc[nt] = __builtin_amdgcn_mfma_f32_16x16x32_f16(a, b, acc[nt], 0, 0, 0);
        }
    }

    int row_base = n0 + m0 + q * 4;                     // C/D: col=lane&15, row=q*4+reg
#pragma unroll
    for (int nt = 0; nt < NT; ++nt) {
#pragma unroll
        for (int r = 0; r < 4; ++r) {
            int row = row_base + r;
            if (row < N_NODES)
                Y[(size_t)row * 128 + nt * 16 + l15] = f2fp8(acc[nt][r]);
        }
    }
}

// ---- aggregation L1 FUSED with GEMM2. M1 fp8 rows (128B). Each wave aggregates
// ---- 4 nodes (full-wave gathers, 16 in flight), h1s -> LDS f16, then
// ---- 16x64 MFMA vs W2^T -> M2 fp8.
__global__ __launch_bounds__(256) void aggregate1_fused(const ushort* __restrict__ M,
                                                        const int* __restrict__ row_start,
                                                        const int* __restrict__ row_end,
                                                        const int* __restrict__ csr_src,
                                                        const float* __restrict__ dis,
                                                        const float* __restrict__ bias,
                                                        const f16* __restrict__ W2t,
                                                        uchar* __restrict__ M2) {
    constexpr int PITCH = 136;            // sB pitch in f16
    constexpr int HP = 130;               // sH pitch in f16 (65 uints)
    __shared__ f16 sB[64 * PITCH];
    __shared__ f16 sH[16 * HP];
    int tid = threadIdx.x;
    // stage W2^T [64 out][128 k]
    for (int i = tid; i < 64 * 16; i += 256) {
        int r = i >> 4, c = i & 15;
        *(uint4*)&sB[r * PITCH + c * 8] = ((const uint4*)(W2t + r * 128))[c];
    }
    int wv = __builtin_amdgcn_readfirstlane((int)(tid >> 6));
    int lane = tid & 63;
    int n0 = blockIdx.x * 16;             // 100000 = 6250 * 16 exactly

    for (int i = 0; i < 4; ++i) {
        int r = wv * 4 + i;
        int n = n0 + r;
        float dn = dis[n];
        int e0 = row_start[n], e1 = row_end[n];
        f32x2 t0 = __builtin_amdgcn_cvt_pk_f32_fp8((int)M[(size_t)n * 64 + lane], false);
        float a0 = t0.x, a1 = t0.y, b0 = 0.f, b1v = 0.f;
        int e = e0;
        for (; e + 16 <= e1; e += 16) {
            int s[16];
#pragma unroll
            for (int j = 0; j < 16; ++j) s[j] = csr_src[e + j];
            ushort v[16];
#pragma unroll
            for (int j = 0; j < 16; ++j) v[j] = M[(size_t)s[j] * 64 + lane];
#pragma unroll
            for (int j = 0; j < 16; ++j) {
                f32x2 f = __builtin_amdgcn_cvt_pk_f32_fp8((int)v[j], false);
                if (j & 1) { b0 += f.x; b1v += f.y; } else { a0 += f.x; a1 += f.y; }
            }
        }
        for (; e + 8 <= e1; e += 8) {
            int s[8];
#pragma unroll
            for (int j = 0; j < 8; ++j) s[j] = csr_src[e + j];
            ushort v[8];
#pragma unroll
            for (int j = 0; j < 8; ++j) v[j] = M[(size_t)s[j] * 64 + lane];
#pragma unroll
            for (int j = 0; j < 8; ++j) {
                f32x2 f = __builtin_amdgcn_cvt_pk_f32_fp8((int)v[j], false);
                if (j & 1) { b0 += f.x; b1v += f.y; } else { a0 += f.x; a1 += f.y; }
            }
        }
        for (; e + 4 <= e1; e += 4) {
            int s0 = csr_src[e], s1 = csr_src[e + 1], s2 = csr_src[e + 2], s3 = csr_src[e + 3];
            ushort v0 = M[(size_t)s0 * 64 + lane];
            ushort v1 = M[(size_t)s1 * 64 + lane];
            ushort v2 = M[(size_t)s2 * 64 + lane];
            ushort v3 = M[(size_t)s3 * 64 + lane];
            f32x2 f0 = __builtin_amdgcn_cvt_pk_f32_fp8((int)v0, false);
            f32x2 f1 = __builtin_amdgcn_cvt_pk_f32_fp8((int)v1, false);
            f32x2 f2 = __builtin_amdgcn_cvt_pk_f32_fp8((int)v2, false);
            f32x2 f3 = __builtin_amdgcn_cvt_pk_f32_fp8((int)v3, false);
            a0 += f0.x + f1.x; a1 += f0.y + f1.y;
            b0 += f2.x + f3.x; b1v += f2.y + f3.y;
        }
        for (; e < e1; ++e) {
            f32x2 f = __builtin_amdgcn_cvt_pk_f32_fp8((int)M[(size_t)csr_src[e] * 64 + lane], false);
            a0 += f.x; a1 += f.y;
        }
        a0 += b0; a1 += b1v;
        a0 = fmaxf(fmaf(a0, dn, bias[2 * lane]), 0.f) * dn;
        a1 = fmaxf(fmaf(a1, dn, bias[2 * lane + 1]), 0.f) * dn;
        *(uint*)&sH[r * HP + 2 * lane] = packf16(a0, a1);   // h1s row r in LDS (f16)
    }
    __syncthreads();

    // MFMA: C[16 nodes][64 out] ; wave wv covers out cols wv*16..wv*16+15
    int l15 = lane & 15, q = lane >> 4;
    f32x4 acc = (f32x4){0.f, 0.f, 0.f, 0.f};
    const f16* pa = &sH[l15 * HP + q * 8];
    const f16* pb = &sB[(wv * 16 + l15) * PITCH + q * 8];
#pragma unroll
    for (int kk = 0; kk < 4; ++kk) {
        f16x8 a = *(const f16x8*)(pa + kk * 32);
        f16x8 b = *(const f16x8*)(pb + kk * 32);
        acc = __builtin_amdgcn_mfma_f32_16x16x32_f16(a, b, acc, 0, 0, 0);
    }
    int row_base = n0 + q * 4;                    // C/D: col=lane&15, row=q*4+reg
#pragma unroll
    for (int rr = 0; rr < 4; ++rr)
        M2[(size_t)(row_base + rr) * 64 + wv * 16 + l15] = f2fp8(acc[rr]);
}

// ---- aggregation L2 + pooling via atomics: 1 wave per node (full parallelism).
// ---- M2 fp8 rows = 64B = one line per edge; 16 in flight. h2 row stays in
// ---- registers; relu'd value atomicAdd'ed into pooled[batch[n]]. No h2 buffer. ----
__global__ __launch_bounds__(256) void aggregate2(const uchar* __restrict__ M,
                                                  const int* __restrict__ row_start,
                                                  const int* __restrict__ row_end,
                                                  const int* __restrict__ csr_src,
                                                  const float* __restrict__ dis,
                                                  const float* __restrict__ bias,
                                                  const int* __restrict__ batch,
                                                  float* __restrict__ pooled) {
    int wv = __builtin_amdgcn_readfirstlane((int)(threadIdx.x >> 6));
    int n = blockIdx.x * 4 + wv;
    if (n >= N_NODES) return;
    int lane = threadIdx.x & 63;
    float dn = dis[n];
    int e0 = row_start[n], e1 = row_end[n];
    float a0 = __builtin_amdgcn_cvt_f32_fp8((int)M[(size_t)n * 64 + lane], 0);  // self-loop
    float a1 = 0.f;
    int e = e0;
    for (; e + 16 <= e1; e += 16) {
        int s[16];
#pragma unroll
        for (int j = 0; j < 16; ++j) s[j] = csr_src[e + j];
        uchar v[16];
#pragma unroll
        for (int j = 0; j < 16; ++j) v[j] = M[(size_t)s[j] * 64 + lane];
#pragma unroll
        for (int j = 0; j < 16; ++j) {
            float f = __builtin_amdgcn_cvt_f32_fp8((int)v[j], 0);
            if (j & 1) a1 += f; else a0 += f;
        }
    }
    for (; e + 8 <= e1; e += 8) {
        int s[8];
#pragma unroll
        for (int j = 0; j < 8; ++j) s[j] = csr_src[e + j];
        uchar v[8];
#pragma unroll
        for (int j = 0; j < 8; ++j) v[j] = M[(size_t)s[j] * 64 + lane];
#pragma unroll
        for (int j = 0; j < 8; ++j) {
            float f = __builtin_amdgcn_cvt_f32_fp8((int)v[j], 0);
            if (j & 1) a1 += f; else a0 += f;
        }
    }
    for (; e + 4 <= e1; e += 4) {
        int s0 = csr_src[e], s1 = csr_src[e + 1], s2 = csr_src[e + 2], s3 = csr_src[e + 3];
        float v0 = __builtin_amdgcn_cvt_f32_fp8((int)M[(size_t)s0 * 64 + lane], 0);
        float v1 = __builtin_amdgcn_cvt_f32_fp8((int)M[(size_t)s1 * 64 + lane], 0);
        float v2 = __builtin_amdgcn_cvt_f32_fp8((int)M[(size_t)s2 * 64 + lane], 0);
        float v3 = __builtin_amdgcn_cvt_f32_fp8((int)M[(size_t)s3 * 64 + lane], 0);
        a0 += v0 + v1; a1 += v2 + v3;
    }
    for (; e < e1; ++e)
        a0 += __builtin_amdgcn_cvt_f32_fp8((int)M[(size_t)csr_src[e] * 64 + lane], 0);
    a0 += a1;
    a0 = fmaxf(fmaf(a0, dn, bias[lane]), 0.f);
    int g = batch[n];                             // wave-uniform scalar load
    atomicAdd(&pooled[g * 64 + lane], a0);        // fire-and-forget, 2048 lines total
}

// ---------------- BN stats + head fused (single block, 512 threads) ----------------
__global__ __launch_bounds__(512) void bn_head(const float* __restrict__ pooled,
                                               const float* __restrict__ gamma,
                                               const float* __restrict__ beta,
                                               const float* __restrict__ Wo1,
                                               const float* __restrict__ bo1,
                                               const float* __restrict__ Wo2,
                                               const float* __restrict__ bo2,
                                               float* __restrict__ out) {
    __shared__ float sW1[64 * 24];
    __shared__ float sW2[24];
    __shared__ float sb1[24];
    __shared__ float ssc[64];
    __shared__ float ssh[64];
    int tid = threadIdx.x;
    for (int i = tid; i < 64 * 24; i += 512) sW1[i] = Wo1[i];
    if (tid >= 64 && tid < 88) { int k = tid - 64; sW2[k] = Wo2[k]; sb1[k] = bo1[k]; }
    if (tid < 64) {
        float s = 0.f, s2 = 0.f;
        for (int g = 0; g < N_GRAPHS; ++g) {
            float v = pooled[g * 64 + tid];
            s += v;
            s2 = fmaf(v, v, s2);
        }
        float mean = s * (1.0f / N_GRAPHS);
        float var = s2 * (1.0f / N_GRAPHS) - mean * mean;
        float istd = rsqrtf(var + BN_EPS);
        float sc = gamma[tid] * istd;
        ssc[tid] = sc;
        ssh[tid] = beta[tid] - mean * sc;
    }
    __syncthreads();
    int g = tid;                                  // 512 graphs = 512 threads
    float xn[64];
    const float* pr = pooled + g * 64;
#pragma unroll
    for (int j = 0; j < 64; ++j) xn[j] = fmaf(pr[j], ssc[j], ssh[j]);
    float o = bo2[0];
#pragma unroll 4
    for (int k = 0; k < 24; ++k) {
        float h = sb1[k];
#pragma unroll
        for (int j = 0; j < 64; ++j) h = fmaf(xn[j], sW1[j * 24 + k], h);
        o = fmaf(fmaxf(h, 0.f), sW2[k], o);
    }
    out[g] = o;
}

extern "C" void kernel_launch(void* const* d_in, const int* in_sizes, int n_in,
                              void* d_out, int out_size, void* d_ws, size_t ws_size,
                              hipStream_t stream) {
    const float* x     = (const float*)d_in[0];
    const int*   ei    = (const int*)d_in[1];   // [2,E]: first E = src, next E = dst
    const int*   batch = (const int*)d_in[2];
    const float* W1    = (const float*)d_in[3];
    const float* b1    = (const float*)d_in[4];
    const float* W2    = (const float*)d_in[5];
    const float* b2    = (const float*)d_in[6];
    const float* gamma = (const float*)d_in[7];
    const float* beta  = (const float*)d_in[8];
    const float* Wo1   = (const float*)d_in[9];
    const float* bo1   = (const float*)d_in[10];
    const float* Wo2   = (const float*)d_in[11];
    const float* bo2   = (const float*)d_in[12];
    float* out = (float*)d_out;               // [512] out, then [512*64] h(=pooled)
    char* ws = (char*)d_ws;

    const int* srcv = ei;
    const int* dstv = ei + N_EDGES;
    int*    bcur     = (int*)(ws + OFF_BCUR);
    float*  dis      = (float*)(ws + OFF_DIS);
    int*    row_start= (int*)(ws + OFF_ROW);
    int*    row_end  = (int*)(ws + OFF_END);
    f16*    wT       = (f16*)(ws + OFF_WT);
    uint*   binned   = (uint*)(ws + OFF_BIN);
    int*    csr_src  = (int*)(ws + OFF_CSR);
    uchar*  bufP     = (uchar*)(ws + OFF_P);  // M2 (fp8)
    uchar*  bufQ     = (uchar*)(ws + OFF_Q);  // M1 (fp8)
    float*  pooled   = out + N_GRAPHS;        // h output region, also used downstream

    init_prep<<<105, 256, 0, stream>>>(W1, W2, wT, bcur, pooled);
    bin_scatter<<<NCHUNKS, 1024, 0, stream>>>(srcv, dstv, bcur, binned);
    csr_from_bins<<<NBUCKET_USED, 256, 0, stream>>>(binned, bcur, row_start, row_end, dis, csr_src);

    int gblocks = (N_NODES + 63) / 64;
    gemm_mfma1<<<gblocks, 256, 0, stream>>>(x, dis, wT, bufQ);
    aggregate1_fused<<<N_NODES / 16, 256, 0, stream>>>((const ushort*)bufQ, row_start, row_end,
                                                       csr_src, dis, b1, wT + 16384, bufP);
    aggregate2<<<(N_NODES + 3) / 4, 256, 0, stream>>>(bufP, row_start, row_end, csr_src, dis, b2,
                                                      batch, pooled);
    bn_head<<<1, 512, 0, stream>>>(pooled, gamma, beta, Wo1, bo1, Wo2, bo2, out);
}